// Round 15
// baseline (252.710 us; speedup 1.0000x reference)
//
#include <hip/hip_runtime.h>

typedef short bf16x8 __attribute__((ext_vector_type(8)));
typedef unsigned short u16x8 __attribute__((ext_vector_type(8)));
typedef float f32x4 __attribute__((ext_vector_type(4)));
typedef unsigned short u16;

#define MFMA16(a, b, c) __builtin_amdgcn_mfma_f32_16x16x32_bf16((a), (b), (c), 0, 0, 0)
// Full drain before barrier (R4 race lesson).
#define VMCNT0() asm volatile("s_waitcnt vmcnt(0)" ::: "memory")
// Counted wait (T4): allow n per-wave loads to remain in flight.
#define VMCNTN(n) asm volatile("s_waitcnt vmcnt(" #n ")" ::: "memory")

__device__ __forceinline__ u16 bf16_rtn(float f) {
  unsigned u = __float_as_uint(f);
  u += 0x7fffu + ((u >> 16) & 1u);
  return (u16)(u >> 16);
}
__device__ __forceinline__ float bf16_to_f(u16 h) {
  return __uint_as_float(((unsigned)h) << 16);
}
__device__ __forceinline__ void splitf(float f, u16& hi, u16& lo) {
  hi = bf16_rtn(f);
  lo = bf16_rtn(f - bf16_to_f(hi));
}
__device__ __forceinline__ void gload16(const void* g, void* l) {
  __builtin_amdgcn_global_load_lds(
      (const __attribute__((address_space(1))) unsigned int*)g,
      (__attribute__((address_space(3))) unsigned int*)l, 16, 0, 0);
}
__device__ __forceinline__ float exp2_hw(float x) {
  float r;
  asm("v_exp_f32 %0, %1" : "=v"(r) : "v"(x));
  return r;
}
// XCD-aware bijective block swizzle (T1). Requires gx*gy % 8 == 0 (all our grids).
__device__ __forceinline__ void swz_bid(int& bx, int& by) {
  int gx = gridDim.x;
  int lin = (int)blockIdx.y * gx + (int)blockIdx.x;
  int cpx = (gx * (int)gridDim.y) >> 3;
  int nl = (lin & 7) * cpx + (lin >> 3);
  bx = nl % gx;
  by = nl / gx;
}

// ---------------- elementwise convert: kq -> bf16, v -> bf16 ----------------
__global__ void k_cvt(const float* __restrict__ a, const float* __restrict__ b,
                      u16* __restrict__ ah, u16* __restrict__ vb) {
  int i = blockIdx.x * blockDim.x + threadIdx.x;
  const int N4 = 1 << 20;
  const float4 v4 = (i < N4) ? ((const float4*)a)[i] : ((const float4*)b)[i - N4];
  ushort4 h;
  h.x = bf16_rtn(v4.x);
  h.y = bf16_rtn(v4.y);
  h.z = bf16_rtn(v4.z);
  h.w = bf16_rtn(v4.w);
  if (i < N4)
    ((ushort4*)ah)[i] = h;
  else
    ((ushort4*)vb)[i - N4] = h;
}

// ------------- fused transpose of the three 1024x1024 weights -------------
__global__ void k_tconvW(const float* __restrict__ Wk, const float* __restrict__ Wq,
                         const float* __restrict__ Wv, u16* __restrict__ hi,
                         u16* __restrict__ lo, u16* __restrict__ wvt) {
  int z = blockIdx.z;
  const float* in = (z == 0) ? Wk : (z == 1) ? Wq : Wv;
  __shared__ float tile[32][33];
  int c0 = blockIdx.x * 32, r0 = blockIdx.y * 32;
  int tx = threadIdx.x & 31, ty = threadIdx.x >> 5;
#pragma unroll
  for (int i = 0; i < 4; ++i)
    tile[ty + i * 8][tx] = in[(size_t)(r0 + ty + i * 8) * 1024 + c0 + tx];
  __syncthreads();
#pragma unroll
  for (int i = 0; i < 4; ++i) {
    float v = tile[tx][ty + i * 8];
    size_t o = (size_t)(c0 + ty + i * 8) * 1024 + r0 + tx;
    if (z < 2) {
      u16 h, l;
      splitf(v, h, l);
      hi[(size_t)z * 1048576 + o] = h;
      lo[(size_t)z * 1048576 + o] = l;
    } else {
      wvt[o] = bf16_rtn(v);
    }
  }
}

// ------------- transpose fp32 [R][C] -> bf16 [C][R] (plain) -------------
__global__ void k_tconv(const float* __restrict__ in, u16* __restrict__ hi,
                        int R, int C) {
  __shared__ float tile[32][33];
  int c0 = blockIdx.x * 32, r0 = blockIdx.y * 32;
  int tx = threadIdx.x & 31, ty = threadIdx.x >> 5;
#pragma unroll
  for (int i = 0; i < 4; ++i)
    tile[ty + i * 8][tx] = in[(size_t)(r0 + ty + i * 8) * C + c0 + tx];
  __syncthreads();
#pragma unroll
  for (int i = 0; i < 4; ++i)
    hi[(size_t)(c0 + ty + i * 8) * R + r0 + tx] = bf16_rtn(tile[tx][ty + i * 8]);
}

// ------------- non-split GEMM: BM=128, BN in {64,128} -------------
// BK=64, XOR-swizzled LDS, 3-buffer depth-2, counted vmcnt (= loads/wave/tile).
// OUT: 0 = fp32 row-major, 1 = bf16 row-major, 5 = V into swizzled KV slab.
template <int GELU, int OUT, int BN>
__global__ __launch_bounds__(256) void k_gemm(
    const u16* __restrict__ A, const u16* __restrict__ B,
    const float* __restrict__ bias, void* __restrict__ C0,
    int M, int Nc, int K) {
  const int NB = BN / 32;
  const int BUFE = 8192 + BN * 64;
  __shared__ u16 sm[3 * BUFE];

  int bx, by;
  swz_bid(bx, by);
  int m0 = by * 128, n0 = bx * BN;
  int t = threadIdx.x, lane = t & 63, w = t >> 6;
  int wr = (w >> 1) * 64, wc = (w & 1) * (BN / 2);
  int li = lane & 15, g = lane >> 4;
  int lrow = lane >> 3, lcg = lane & 7;

  f32x4 acc[4][NB] = {};
  const int nk = K >> 6;

  auto stage = [&](int kb, int buf) {
    int k0 = kb * 64;
    u16* base = sm + buf * BUFE;
#pragma unroll
    for (int j = 0; j < 4; ++j) {
      int jj = w * 4 + j;
      int row = jj * 8 + lrow;
      int cg = lcg ^ (row & 7);
      gload16(A + (size_t)(m0 + row) * K + k0 + cg * 8, base + jj * 512);
    }
#pragma unroll
    for (int j = 0; j < NB; ++j) {
      int jj = w * NB + j;
      int row = jj * 8 + lrow;
      int cg = lcg ^ (row & 7);
      gload16(B + (size_t)(n0 + row) * K + k0 + cg * 8, base + 8192 + jj * 512);
    }
  };

  stage(0, 0);
  stage(1, 1);
  if (NB == 4) { VMCNTN(8); } else { VMCNTN(6); }  // = loads/wave/tile
  __syncthreads();

  int cur = 0;
  for (int kb = 0; kb < nk; ++kb) {
    int stb = cur + 2;
    if (stb >= 3) stb -= 3;
    if (kb + 2 < nk) stage(kb + 2, stb);

    const u16* bs = sm + cur * BUFE;
#pragma unroll
    for (int kk = 0; kk < 2; ++kk) {
      bf16x8 af[4], bf[NB];
#pragma unroll
      for (int i = 0; i < 4; ++i) {
        int row = wr + i * 16 + li;
        af[i] = *(const bf16x8*)&bs[row * 64 + (((kk * 4 + g) ^ (li & 7)) << 3)];
      }
#pragma unroll
      for (int b = 0; b < NB; ++b) {
        int row = wc + b * 16 + li;
        bf[b] = *(const bf16x8*)&bs[8192 + row * 64 + (((kk * 4 + g) ^ (li & 7)) << 3)];
      }
#pragma unroll
      for (int a = 0; a < 4; ++a)
#pragma unroll
        for (int b = 0; b < NB; ++b) acc[a][b] = MFMA16(af[a], bf[b], acc[a][b]);
    }
    if (kb + 2 < nk) {
      if (NB == 4) { VMCNTN(8); } else { VMCNTN(6); }
    } else {
      VMCNT0();
    }
    __syncthreads();
    cur = (cur == 2) ? 0 : cur + 1;
  }

#pragma unroll
  for (int a = 0; a < 4; ++a)
#pragma unroll
    for (int b = 0; b < NB; ++b)
#pragma unroll
      for (int r = 0; r < 4; ++r) {
        int row = m0 + wr + a * 16 + g * 4 + r;
        int col = n0 + wc + b * 16 + li;
        float v = acc[a][b][r] + bias[col];
        if (GELU) v = 0.5f * v * (1.0f + erff(v * 0.70710678118654752f));
        if (OUT == 0) {
          ((float*)C0)[(size_t)row * Nc + col] = v;
        } else if (OUT == 1) {
          ((u16*)C0)[(size_t)row * Nc + col] = bf16_rtn(v);
        } else if (OUT == 5) {
          int nn = row >> 11, tt = row & 2047, kbb = tt >> 6, tr = tt & 63;
          int hq = col >> 6, d = col & 63;
          size_t base = (((size_t)nn * 16 + hq) * 32 + kbb) * 8192 + 4096;
          size_t ov = base + d * 64 + (tr & 7) + (((tr >> 3) ^ (d & 7)) << 3);
          ((u16*)C0)[ov] = bf16_rtn(v);
        }
      }
}

// ------------- big-tile GEMM: 256x256, 4 waves, per-wave 128x128 -------------
// Frag-reuse fix for the LDS:MFMA imbalance (R12-R14 all ~23% MfmaUtil at
// per-wave 128x64): 8x8 frags/wave -> 128 MFMA per 16 ds_read_b128 per kk ->
// MFMA:LDS = 3.2:1 (2483 vs 768 cyc/CU/tile). BK=64, 2-buffer 128KB LDS,
// R12-proven sync skeleton (stage(kb+1) at tile top, vmcnt(0)+barrier at end —
// drain is free, compute >> HBM latency). acc 256 + frags 64 VGPR < 450
// no-spill threshold at 1 wave/SIMD.
template <int GELU, int OUT>
__global__ __launch_bounds__(256, 1) void k_gemm2(
    const u16* __restrict__ A, const u16* __restrict__ B,
    const float* __restrict__ bias, void* __restrict__ C0,
    int M, int Nc, int K) {
  const int BUFE = 32768;       // u16: A[256][64] | B[256][64]
  __shared__ u16 sm[2 * BUFE];  // 128 KB

  int bx, by;
  swz_bid(bx, by);
  int m0 = by * 256, n0 = bx * 256;
  int t = threadIdx.x, lane = t & 63, w = t >> 6;
  int wr = (w >> 1) * 128, wc = (w & 1) * 128;  // 2M x 2N wave grid
  int li = lane & 15, g = lane >> 4;
  int lrow = lane >> 3, lcg = lane & 7;

  f32x4 acc[8][8] = {};
  const int nk = K >> 6;

  auto stage = [&](int kb, int buf) {
    int k0 = kb * 64;
    u16* base = sm + buf * BUFE;
#pragma unroll
    for (int j = 0; j < 8; ++j) {
      int jj = w * 8 + j;       // 0..31
      int row = jj * 8 + lrow;  // 0..255
      int cg = lcg ^ (row & 7);
      gload16(A + (size_t)(m0 + row) * K + k0 + cg * 8, base + jj * 512);
      gload16(B + (size_t)(n0 + row) * K + k0 + cg * 8, base + 16384 + jj * 512);
    }
  };

  stage(0, 0);
  VMCNT0();
  __syncthreads();

  int cur = 0;
  for (int kb = 0; kb < nk; ++kb) {
    if (kb + 1 < nk) stage(kb + 1, cur ^ 1);  // issued at tile top

    const u16* bs = sm + cur * BUFE;
#pragma unroll
    for (int kk = 0; kk < 2; ++kk) {
      bf16x8 af[8], bf[8];
#pragma unroll
      for (int i = 0; i < 8; ++i) {
        int row = wr + i * 16 + li;
        af[i] = *(const bf16x8*)&bs[row * 64 + (((kk * 4 + g) ^ (li & 7)) << 3)];
      }
#pragma unroll
      for (int b = 0; b < 8; ++b) {
        int row = wc + b * 16 + li;
        bf[b] = *(const bf16x8*)&bs[16384 + row * 64 + (((kk * 4 + g) ^ (li & 7)) << 3)];
      }
#pragma unroll
      for (int a = 0; a < 8; ++a)
#pragma unroll
        for (int b = 0; b < 8; ++b) acc[a][b] = MFMA16(af[a], bf[b], acc[a][b]);
    }
    VMCNT0();         // prefetch landed long ago (compute ~2500 cyc >> latency)
    __syncthreads();
    cur ^= 1;
  }

#pragma unroll
  for (int a = 0; a < 8; ++a)
#pragma unroll
    for (int b = 0; b < 8; ++b)
#pragma unroll
      for (int r = 0; r < 4; ++r) {
        int row = m0 + wr + a * 16 + g * 4 + r;
        int col = n0 + wc + b * 16 + li;
        float v = acc[a][b][r] + bias[col];
        if (GELU) v = 0.5f * v * (1.0f + erff(v * 0.70710678118654752f));
        if (OUT == 1)
          ((u16*)C0)[(size_t)row * Nc + col] = bf16_rtn(v);
        else
          ((float*)C0)[(size_t)row * Nc + col] = v;
      }
}

// ------------- 2-pass split GEMM (K|Q fused projection) -------------
__global__ __launch_bounds__(256) void k_gemm_s(
    const u16* __restrict__ Ahi, const u16* __restrict__ Bhi,
    const u16* __restrict__ Blo, const float* __restrict__ bias,
    const float* __restrict__ bias2, void* __restrict__ C0,
    void* __restrict__ C1, void* __restrict__ C2, int M, int Nc, int K) {
  const int BUFE = 12288;
  __shared__ u16 sm[3 * BUFE];

  int bx, by;
  swz_bid(bx, by);
  int m0 = by * 128, n0 = bx * 128;
  int t = threadIdx.x, lane = t & 63, w = t >> 6;
  int wr = (w >> 1) * 64, wc = (w & 1) * 64;
  int li = lane & 15, g = lane >> 4;
  int srow = lane >> 2;
  int sc = ((lane & 3) ^ ((srow >> 1) & 3)) * 8;

  f32x4 acc[4][4] = {};
  const int nk = K >> 5;

  auto stage = [&](int kb, int buf) {
    int k0 = kb * 32;
    u16* base = sm + buf * BUFE;
#pragma unroll
    for (int c = 0; c < 2; ++c) {
      int row = w * 32 + c * 16 + srow;
      int ldso = w * 1024 + c * 512;
      gload16(Ahi + (size_t)(m0 + row) * K + k0 + sc, base + ldso);
      gload16(Bhi + (size_t)(n0 + row) * K + k0 + sc, base + 4096 + ldso);
      gload16(Blo + (size_t)(n0 + row) * K + k0 + sc, base + 8192 + ldso);
    }
  };

  stage(0, 0);
  stage(1, 1);
  VMCNTN(6);
  __syncthreads();

  int cur = 0;
  for (int kb = 0; kb < nk; ++kb) {
    int stb = cur + 2;
    if (stb >= 3) stb -= 3;
    if (kb + 2 < nk) stage(kb + 2, stb);

    const u16* bs = sm + cur * BUFE;
    bf16x8 af[4], bfr[4], bfl[4];
#pragma unroll
    for (int i = 0; i < 4; ++i) {
      int swz = (g ^ ((li >> 1) & 3)) << 3;
      af[i] = *(const bf16x8*)&bs[(wr + i * 16 + li) * 32 + swz];
      bfr[i] = *(const bf16x8*)&bs[4096 + (wc + i * 16 + li) * 32 + swz];
      bfl[i] = *(const bf16x8*)&bs[8192 + (wc + i * 16 + li) * 32 + swz];
    }
#pragma unroll
    for (int a = 0; a < 4; ++a)
#pragma unroll
      for (int b = 0; b < 4; ++b) {
        acc[a][b] = MFMA16(af[a], bfr[b], acc[a][b]);
        acc[a][b] = MFMA16(af[a], bfl[b], acc[a][b]);
      }
    if (kb + 2 < nk) {
      VMCNTN(6);
    } else {
      VMCNT0();
    }
    __syncthreads();
    cur = (cur == 2) ? 0 : cur + 1;
  }

#pragma unroll
  for (int a = 0; a < 4; ++a)
#pragma unroll
    for (int b = 0; b < 4; ++b)
#pragma unroll
      for (int r = 0; r < 4; ++r) {
        int row = m0 + wr + a * 16 + g * 4 + r;
        int col = n0 + wc + b * 16 + li;
        float bb = col < 1024 ? bias[col] : bias2[col - 1024];
        float v = acc[a][b][r] + bb;
        if (col < 1024) {
          int nn = row >> 11, tt = row & 2047, kbb = tt >> 6, tr = tt & 63;
          int hq = col >> 6, d = col & 63, ks = d >> 5, dc = d & 31;
          size_t base = (((size_t)nn * 16 + hq) * 32 + kbb) * 8192;
          size_t oh = base + ks * 2048 + tr * 32 + (dc & 7) +
                      (((dc >> 3) ^ ((tr >> 1) & 3)) << 3);
          ((u16*)C0)[oh] = bf16_rtn(v);
        } else {
          int cq = col - 1024;
          float vq = v * 1.4426950408889634f;
          u16 hh, ll;
          splitf(vq, hh, ll);
          size_t off = (((size_t)(row >> 11) * 16 + (cq >> 6)) * 2048 + (row & 2047)) * 64 + (cq & 63);
          ((u16*)C1)[off] = hh;
          ((u16*)C2)[off] = ll;
        }
      }
}

// ------------- flash attention, strictly-causal + [0,0], no 1/sqrt(d) -------------
__global__ __launch_bounds__(512) void k_attn(
    const u16* __restrict__ Qh, const u16* __restrict__ Ql,
    const u16* __restrict__ KV, u16* __restrict__ out) {
  const int T = 2048, HD = 64, H = 16, E = 1024;
  int hc = blockIdx.x;
  int h = hc & 15, n = hc >> 4;
  int qq = 15 - (int)blockIdx.y;
  __shared__ u16 KB[3][8192];
  __shared__ u16 P[2][128][36];
  int t = threadIdx.x, lane = t & 63, w = t >> 6;
  int li = lane & 15, g = lane >> 4;

  const size_t nh = (size_t)n * H + h;
  const u16* qhb = Qh + (nh * 2048 + (size_t)qq * 128) * 64;
  const u16* qlb = Ql + (nh * 2048 + (size_t)qq * 128) * 64;
  const u16* kvb = KV + nh * 32 * 8192;

  bf16x8 qh[2], ql[2];
#pragma unroll
  for (int ks = 0; ks < 2; ++ks) {
    qh[ks] = *(const bf16x8*)&qhb[(w * 16 + li) * 64 + ks * 32 + g * 8];
    ql[ks] = *(const bf16x8*)&qlb[(w * 16 + li) * 64 + ks * 32 + g * 8];
  }

#pragma unroll
  for (int j = 0; j < 2; ++j)
    gload16(kvb + (w * 2 + j) * 512 + lane * 8, &KB[0][(w * 2 + j) * 512]);
#pragma unroll
  for (int j = 0; j < 2; ++j)
    gload16(kvb + 8192 + (w * 2 + j) * 512 + lane * 8, &KB[1][(w * 2 + j) * 512]);
  VMCNTN(2);
  __syncthreads();

  float lr[4] = {0.f, 0.f, 0.f, 0.f};
  f32x4 O[4] = {};
  int cur = 0;
  const int nkb = 2 * qq + 2;

  for (int kb = 0; kb < nkb; ++kb) {
    int stb = cur + 2;
    if (stb >= 3) stb -= 3;
    if (kb + 2 < nkb) {
      const u16* src = kvb + (size_t)(kb + 2) * 8192 + (w * 2) * 512 + lane * 8;
#pragma unroll
      for (int j = 0; j < 2; ++j)
        gload16(src + j * 512, &KB[stb][(w * 2 + j) * 512]);
    }

    f32x4 s[4] = {};
#pragma unroll
    for (int ks = 0; ks < 2; ++ks)
#pragma unroll
      for (int c = 0; c < 4; ++c) {
        int jr = c * 16 + li;
        int sw = (jr >> 1) & 3;
        bf16x8 kh = *(const bf16x8*)&KB[cur][ks * 2048 + jr * 32 + ((g ^ sw) << 3)];
        s[c] = MFMA16(qh[ks], kh, s[c]);
        s[c] = MFMA16(ql[ks], kh, s[c]);
      }

    if (kb >= 2 * qq) {
#pragma unroll
      for (int c = 0; c < 4; ++c)
#pragma unroll
        for (int r = 0; r < 4; ++r) {
          int i = qq * 128 + w * 16 + g * 4 + r;
          int j = kb * 64 + c * 16 + li;
          if (!(j < i || (i == 0 && j == 0))) s[c][r] = -INFINITY;
        }
    }

#pragma unroll
    for (int c = 0; c < 4; ++c)
#pragma unroll
      for (int r = 0; r < 4; ++r) {
        float p = exp2_hw(s[c][r]);
        s[c][r] = p;
        lr[r] += p;
      }

#pragma unroll
    for (int c = 0; c < 4; ++c)
#pragma unroll
      for (int r = 0; r < 4; ++r)
        P[c >> 1][w * 16 + g * 4 + r][(c & 1) * 16 + li] = bf16_rtn(s[c][r]);

#pragma unroll
    for (int ks = 0; ks < 2; ++ks) {
      bf16x8 pa = *(const bf16x8*)&P[ks][w * 16 + li][g * 8];
#pragma unroll
      for (int c = 0; c < 4; ++c) {
        int d = c * 16 + li;
        int tc = ks * 4 + g;
        bf16x8 vb = *(const bf16x8*)&KB[cur][4096 + d * 64 + ((tc ^ (d & 7)) << 3)];
        O[c] = MFMA16(pa, vb, O[c]);
      }
    }
    if (kb + 2 < nkb) {
      VMCNTN(2);
    } else {
      VMCNT0();
    }
    __syncthreads();
    cur = (cur == 2) ? 0 : cur + 1;
  }

#pragma unroll
  for (int off = 1; off < 16; off <<= 1)
#pragma unroll
    for (int r = 0; r < 4; ++r) lr[r] += __shfl_xor(lr[r], off, 16);

#pragma unroll
  for (int c = 0; c < 4; ++c)
#pragma unroll
    for (int r = 0; r < 4; ++r) {
      float v = O[c][r] / lr[r];
      size_t row = (size_t)n * T + qq * 128 + w * 16 + g * 4 + r;
      out[row * E + h * HD + c * 16 + li] = bf16_rtn(v);
    }
}

// ---------------------------------------------------------------------------
extern "C" void kernel_launch(void* const* d_in, const int* in_sizes, int n_in,
                              void* d_out, int out_size, void* d_ws, size_t ws_size,
                              hipStream_t stream) {
  const float* kq = (const float*)d_in[0];
  const float* v = (const float*)d_in[1];
  const float* Wk = (const float*)d_in[2];
  const float* bk = (const float*)d_in[3];
  const float* Wq = (const float*)d_in[4];
  const float* bq = (const float*)d_in[5];
  const float* Wv = (const float*)d_in[6];
  const float* bv = (const float*)d_in[7];
  const float* W1 = (const float*)d_in[8];
  const float* b1 = (const float*)d_in[9];
  const float* W2 = (const float*)d_in[10];
  const float* b2 = (const float*)d_in[11];
  float* outp = (float*)d_out;

  char* ws = (char*)d_ws;
  u16* kq_hi = (u16*)(ws + 0);
  u16* v_bf = (u16*)(ws + 8388608);
  u16* hbuf = (u16*)(ws + 0);  // 32MB, aliases kq_hi/v_bf after attention
  u16* WkqT_hi = (u16*)(ws + 33554432);  // 4MB: [WkT | WqT]
  u16* WkqT_lo = (u16*)(ws + 37748736);  // 4MB
  u16* WvT = (u16*)(ws + 41943040);
  u16* W1T = (u16*)(ws + 44040192);
  u16* W2T = (u16*)(ws + 52428800);
  u16* Qh = (u16*)(ws + 60817408);
  u16* Ql = (u16*)(ws + 69206016);
  u16* KV = (u16*)(ws + 77594624);  // 16MB: 1024 slabs x 16KB (K hi + V)
  u16* attn_o = (u16*)(ws + 102760448);
  // total: 111,149,056 bytes

  // --- conversions ---
  k_cvt<<<8192, 256, 0, stream>>>(kq, v, kq_hi, v_bf);
  k_tconvW<<<dim3(32, 32, 3), 256, 0, stream>>>(Wk, Wq, Wv, WkqT_hi, WkqT_lo, WvT);
  k_tconv<<<dim3(128, 32), 256, 0, stream>>>(W1, W1T, 1024, 4096);
  k_tconv<<<dim3(32, 128), 256, 0, stream>>>(W2, W2T, 4096, 1024);

  // --- fused K|Q projection (2-pass split, 3-buf counted vmcnt, XCD swz) ---
  k_gemm_s<<<dim3(16, 32), 256, 0, stream>>>(
      kq_hi, WkqT_hi, WkqT_lo, bk, bq, KV, Qh, Ql, 4096, 2048, 1024);
  // --- V projection ---
  k_gemm<0, 5, 64><<<dim3(16, 32), 256, 0, stream>>>(
      v_bf, WvT, bv, KV, 4096, 1024, 1024);

  // --- attention ---
  k_attn<<<dim3(32, 16), 512, 0, stream>>>(Qh, Ql, KV, attn_o);

  // --- FFN ---
  // FFN1: 256x256, 4 waves, per-wave 128x128 (frag-reuse: MFMA:LDS = 3.2:1)
  k_gemm2<1, 1><<<dim3(16, 16), 256, 0, stream>>>(
      attn_o, W1T, b1, hbuf, 4096, 4096, 1024);
  // FFN2: BN=128
  k_gemm<0, 0, 128><<<dim3(8, 32), 256, 0, stream>>>(
      hbuf, W2T, b2, outp, 4096, 1024, 4096);
}

// Round 16
// 213.629 us; speedup vs baseline: 1.1829x; 1.1829x over previous
//
#include <hip/hip_runtime.h>

typedef short bf16x8 __attribute__((ext_vector_type(8)));
typedef unsigned short u16x8 __attribute__((ext_vector_type(8)));
typedef float f32x4 __attribute__((ext_vector_type(4)));
typedef unsigned short u16;

#define MFMA16(a, b, c) __builtin_amdgcn_mfma_f32_16x16x32_bf16((a), (b), (c), 0, 0, 0)
// Full drain before barrier (R4 race lesson).
#define VMCNT0() asm volatile("s_waitcnt vmcnt(0)" ::: "memory")
// Counted wait (T4): allow n per-wave loads to remain in flight.
#define VMCNTN(n) asm volatile("s_waitcnt vmcnt(" #n ")" ::: "memory")

__device__ __forceinline__ u16 bf16_rtn(float f) {
  unsigned u = __float_as_uint(f);
  u += 0x7fffu + ((u >> 16) & 1u);
  return (u16)(u >> 16);
}
__device__ __forceinline__ float bf16_to_f(u16 h) {
  return __uint_as_float(((unsigned)h) << 16);
}
__device__ __forceinline__ void splitf(float f, u16& hi, u16& lo) {
  hi = bf16_rtn(f);
  lo = bf16_rtn(f - bf16_to_f(hi));
}
__device__ __forceinline__ void gload16(const void* g, void* l) {
  __builtin_amdgcn_global_load_lds(
      (const __attribute__((address_space(1))) unsigned int*)g,
      (__attribute__((address_space(3))) unsigned int*)l, 16, 0, 0);
}
__device__ __forceinline__ float exp2_hw(float x) {
  float r;
  asm("v_exp_f32 %0, %1" : "=v"(r) : "v"(x));
  return r;
}
// tanh-form GELU via exp2+rcp (~7 VALU ops vs ~25 for erff; max diff vs exact
// erf-GELU ~3e-4 -> ~5e-4 at the output through W2 — negligible vs margin).
__device__ __forceinline__ float gelu_t(float x) {
  float u = x * x;
  float z2 = x * fmaf(u, 0.10294407f, 2.30222726f);  // 2*log2e*0.79788456*(1, 0.044715)
  float den = exp2_hw(z2) + 1.0f;
  float s = __builtin_amdgcn_rcpf(den);
  return fmaf(-x, s, x);  // x*(1 - sigmoid') = gelu_tanh(x)
}
// XCD-aware bijective block swizzle (T1). Requires gx*gy % 8 == 0 (all our grids).
__device__ __forceinline__ void swz_bid(int& bx, int& by) {
  int gx = gridDim.x;
  int lin = (int)blockIdx.y * gx + (int)blockIdx.x;
  int cpx = (gx * (int)gridDim.y) >> 3;
  int nl = (lin & 7) * cpx + (lin >> 3);
  bx = nl % gx;
  by = nl / gx;
}

// ---------------- elementwise convert: kq -> bf16, v -> bf16 ----------------
__global__ void k_cvt(const float* __restrict__ a, const float* __restrict__ b,
                      u16* __restrict__ ah, u16* __restrict__ vb) {
  int i = blockIdx.x * blockDim.x + threadIdx.x;
  const int N4 = 1 << 20;
  const float4 v4 = (i < N4) ? ((const float4*)a)[i] : ((const float4*)b)[i - N4];
  ushort4 h;
  h.x = bf16_rtn(v4.x);
  h.y = bf16_rtn(v4.y);
  h.z = bf16_rtn(v4.z);
  h.w = bf16_rtn(v4.w);
  if (i < N4)
    ((ushort4*)ah)[i] = h;
  else
    ((ushort4*)vb)[i - N4] = h;
}

// ------------- fused transpose of the three 1024x1024 weights -------------
__global__ void k_tconvW(const float* __restrict__ Wk, const float* __restrict__ Wq,
                         const float* __restrict__ Wv, u16* __restrict__ hi,
                         u16* __restrict__ lo, u16* __restrict__ wvt) {
  int z = blockIdx.z;
  const float* in = (z == 0) ? Wk : (z == 1) ? Wq : Wv;
  __shared__ float tile[32][33];
  int c0 = blockIdx.x * 32, r0 = blockIdx.y * 32;
  int tx = threadIdx.x & 31, ty = threadIdx.x >> 5;
#pragma unroll
  for (int i = 0; i < 4; ++i)
    tile[ty + i * 8][tx] = in[(size_t)(r0 + ty + i * 8) * 1024 + c0 + tx];
  __syncthreads();
#pragma unroll
  for (int i = 0; i < 4; ++i) {
    float v = tile[tx][ty + i * 8];
    size_t o = (size_t)(c0 + ty + i * 8) * 1024 + r0 + tx;
    if (z < 2) {
      u16 h, l;
      splitf(v, h, l);
      hi[(size_t)z * 1048576 + o] = h;
      lo[(size_t)z * 1048576 + o] = l;
    } else {
      wvt[o] = bf16_rtn(v);
    }
  }
}

// ------------- transpose fp32 [R][C] -> bf16 [C][R] (plain) -------------
__global__ void k_tconv(const float* __restrict__ in, u16* __restrict__ hi,
                        int R, int C) {
  __shared__ float tile[32][33];
  int c0 = blockIdx.x * 32, r0 = blockIdx.y * 32;
  int tx = threadIdx.x & 31, ty = threadIdx.x >> 5;
#pragma unroll
  for (int i = 0; i < 4; ++i)
    tile[ty + i * 8][tx] = in[(size_t)(r0 + ty + i * 8) * C + c0 + tx];
  __syncthreads();
#pragma unroll
  for (int i = 0; i < 4; ++i)
    hi[(size_t)(c0 + ty + i * 8) * R + r0 + tx] = bf16_rtn(tile[tx][ty + i * 8]);
}

// ------------- non-split GEMM: BM=128, BN in {64,128} -------------
// BK=64, XOR-swizzled LDS, 3-buffer depth-2, counted vmcnt (= loads/wave/tile).
// OUT: 0 = fp32 row-major, 1 = bf16 row-major, 5 = V into swizzled KV slab.
template <int GELU, int OUT, int BN>
__global__ __launch_bounds__(256) void k_gemm(
    const u16* __restrict__ A, const u16* __restrict__ B,
    const float* __restrict__ bias, void* __restrict__ C0,
    int M, int Nc, int K) {
  const int NB = BN / 32;
  const int BUFE = 8192 + BN * 64;
  __shared__ u16 sm[3 * BUFE];

  int bx, by;
  swz_bid(bx, by);
  int m0 = by * 128, n0 = bx * BN;
  int t = threadIdx.x, lane = t & 63, w = t >> 6;
  int wr = (w >> 1) * 64, wc = (w & 1) * (BN / 2);
  int li = lane & 15, g = lane >> 4;
  int lrow = lane >> 3, lcg = lane & 7;

  f32x4 acc[4][NB] = {};
  const int nk = K >> 6;

  auto stage = [&](int kb, int buf) {
    int k0 = kb * 64;
    u16* base = sm + buf * BUFE;
#pragma unroll
    for (int j = 0; j < 4; ++j) {
      int jj = w * 4 + j;
      int row = jj * 8 + lrow;
      int cg = lcg ^ (row & 7);
      gload16(A + (size_t)(m0 + row) * K + k0 + cg * 8, base + jj * 512);
    }
#pragma unroll
    for (int j = 0; j < NB; ++j) {
      int jj = w * NB + j;
      int row = jj * 8 + lrow;
      int cg = lcg ^ (row & 7);
      gload16(B + (size_t)(n0 + row) * K + k0 + cg * 8, base + 8192 + jj * 512);
    }
  };

  stage(0, 0);
  stage(1, 1);
  if (NB == 4) { VMCNTN(8); } else { VMCNTN(6); }  // = loads/wave/tile
  __syncthreads();

  int cur = 0;
  for (int kb = 0; kb < nk; ++kb) {
    int stb = cur + 2;
    if (stb >= 3) stb -= 3;
    if (kb + 2 < nk) stage(kb + 2, stb);

    const u16* bs = sm + cur * BUFE;
#pragma unroll
    for (int kk = 0; kk < 2; ++kk) {
      bf16x8 af[4], bf[NB];
#pragma unroll
      for (int i = 0; i < 4; ++i) {
        int row = wr + i * 16 + li;
        af[i] = *(const bf16x8*)&bs[row * 64 + (((kk * 4 + g) ^ (li & 7)) << 3)];
      }
#pragma unroll
      for (int b = 0; b < NB; ++b) {
        int row = wc + b * 16 + li;
        bf[b] = *(const bf16x8*)&bs[8192 + row * 64 + (((kk * 4 + g) ^ (li & 7)) << 3)];
      }
#pragma unroll
      for (int a = 0; a < 4; ++a)
#pragma unroll
        for (int b = 0; b < NB; ++b) acc[a][b] = MFMA16(af[a], bf[b], acc[a][b]);
    }
    if (kb + 2 < nk) {
      if (NB == 4) { VMCNTN(8); } else { VMCNTN(6); }
    } else {
      VMCNT0();
    }
    __syncthreads();
    cur = (cur == 2) ? 0 : cur + 1;
  }

#pragma unroll
  for (int a = 0; a < 4; ++a)
#pragma unroll
    for (int b = 0; b < NB; ++b)
#pragma unroll
      for (int r = 0; r < 4; ++r) {
        int row = m0 + wr + a * 16 + g * 4 + r;
        int col = n0 + wc + b * 16 + li;
        float v = acc[a][b][r] + bias[col];
        if (GELU) v = gelu_t(v);
        if (OUT == 0) {
          ((float*)C0)[(size_t)row * Nc + col] = v;
        } else if (OUT == 1) {
          ((u16*)C0)[(size_t)row * Nc + col] = bf16_rtn(v);
        } else if (OUT == 5) {
          int nn = row >> 11, tt = row & 2047, kbb = tt >> 6, tr = tt & 63;
          int hq = col >> 6, d = col & 63;
          size_t base = (((size_t)nn * 16 + hq) * 32 + kbb) * 8192 + 4096;
          size_t ov = base + d * 64 + (tr & 7) + (((tr >> 3) ^ (d & 7)) << 3);
          ((u16*)C0)[ov] = bf16_rtn(v);
        }
      }
}

// ------------- big-tile GEMM: 256x256, 8 waves, BK=64 (R12-proven) -------------
// 2-buffer 128KB LDS, stage(kb+1) at tile top, vmcnt(0)+barrier at tile end
// (drain free: compute ~2500 cyc >> HBM latency). Per-wave 128x64 output.
// Best-measured FFN1 config (56.4 us); R13/R14/R15 schedule variants all lost.
template <int GELU, int OUT>
__global__ __launch_bounds__(512, 1) void k_gemm2(
    const u16* __restrict__ A, const u16* __restrict__ B,
    const float* __restrict__ bias, void* __restrict__ C0,
    int M, int Nc, int K) {
  const int BUFE = 32768;       // u16: A[256][64] | B[256][64]
  __shared__ u16 sm[2 * BUFE];  // 128 KB

  int bx, by;
  swz_bid(bx, by);
  int m0 = by * 256, n0 = bx * 256;
  int t = threadIdx.x, lane = t & 63, w = t >> 6;
  int wr = (w >> 2) * 128, wc = (w & 3) * 64;  // 2M x 4N wave grid
  int li = lane & 15, g = lane >> 4;
  int lrow = lane >> 3, lcg = lane & 7;

  f32x4 acc[8][4] = {};
  const int nk = K >> 6;

  auto stage = [&](int kb, int buf) {
    int k0 = kb * 64;
    u16* base = sm + buf * BUFE;
#pragma unroll
    for (int j = 0; j < 4; ++j) {
      int jj = w * 4 + j;       // 0..31
      int row = jj * 8 + lrow;  // 0..255
      int cg = lcg ^ (row & 7);
      gload16(A + (size_t)(m0 + row) * K + k0 + cg * 8, base + jj * 512);
      gload16(B + (size_t)(n0 + row) * K + k0 + cg * 8, base + 16384 + jj * 512);
    }
  };

  stage(0, 0);
  VMCNT0();
  __syncthreads();

  int cur = 0;
  for (int kb = 0; kb < nk; ++kb) {
    if (kb + 1 < nk) stage(kb + 1, cur ^ 1);  // issued at tile top

    const u16* bs = sm + cur * BUFE;
#pragma unroll
    for (int kk = 0; kk < 2; ++kk) {
      bf16x8 af[8], bf[4];
#pragma unroll
      for (int i = 0; i < 8; ++i) {
        int row = wr + i * 16 + li;
        af[i] = *(const bf16x8*)&bs[row * 64 + (((kk * 4 + g) ^ (li & 7)) << 3)];
      }
#pragma unroll
      for (int b = 0; b < 4; ++b) {
        int row = wc + b * 16 + li;
        bf[b] = *(const bf16x8*)&bs[16384 + row * 64 + (((kk * 4 + g) ^ (li & 7)) << 3)];
      }
#pragma unroll
      for (int a = 0; a < 8; ++a)
#pragma unroll
        for (int b = 0; b < 4; ++b) acc[a][b] = MFMA16(af[a], bf[b], acc[a][b]);
    }
    VMCNT0();         // prefetch landed long ago (compute >> latency)
    __syncthreads();
    cur ^= 1;
  }

#pragma unroll
  for (int a = 0; a < 8; ++a)
#pragma unroll
    for (int b = 0; b < 4; ++b)
#pragma unroll
      for (int r = 0; r < 4; ++r) {
        int row = m0 + wr + a * 16 + g * 4 + r;
        int col = n0 + wc + b * 16 + li;
        float v = acc[a][b][r] + bias[col];
        if (GELU) v = gelu_t(v);
        if (OUT == 1)
          ((u16*)C0)[(size_t)row * Nc + col] = bf16_rtn(v);
        else
          ((float*)C0)[(size_t)row * Nc + col] = v;
      }
}

// ------------- 2-pass split GEMM (K|Q fused projection) -------------
__global__ __launch_bounds__(256) void k_gemm_s(
    const u16* __restrict__ Ahi, const u16* __restrict__ Bhi,
    const u16* __restrict__ Blo, const float* __restrict__ bias,
    const float* __restrict__ bias2, void* __restrict__ C0,
    void* __restrict__ C1, void* __restrict__ C2, int M, int Nc, int K) {
  const int BUFE = 12288;
  __shared__ u16 sm[3 * BUFE];

  int bx, by;
  swz_bid(bx, by);
  int m0 = by * 128, n0 = bx * 128;
  int t = threadIdx.x, lane = t & 63, w = t >> 6;
  int wr = (w >> 1) * 64, wc = (w & 1) * 64;
  int li = lane & 15, g = lane >> 4;
  int srow = lane >> 2;
  int sc = ((lane & 3) ^ ((srow >> 1) & 3)) * 8;

  f32x4 acc[4][4] = {};
  const int nk = K >> 5;

  auto stage = [&](int kb, int buf) {
    int k0 = kb * 32;
    u16* base = sm + buf * BUFE;
#pragma unroll
    for (int c = 0; c < 2; ++c) {
      int row = w * 32 + c * 16 + srow;
      int ldso = w * 1024 + c * 512;
      gload16(Ahi + (size_t)(m0 + row) * K + k0 + sc, base + ldso);
      gload16(Bhi + (size_t)(n0 + row) * K + k0 + sc, base + 4096 + ldso);
      gload16(Blo + (size_t)(n0 + row) * K + k0 + sc, base + 8192 + ldso);
    }
  };

  stage(0, 0);
  stage(1, 1);
  VMCNTN(6);
  __syncthreads();

  int cur = 0;
  for (int kb = 0; kb < nk; ++kb) {
    int stb = cur + 2;
    if (stb >= 3) stb -= 3;
    if (kb + 2 < nk) stage(kb + 2, stb);

    const u16* bs = sm + cur * BUFE;
    bf16x8 af[4], bfr[4], bfl[4];
#pragma unroll
    for (int i = 0; i < 4; ++i) {
      int swz = (g ^ ((li >> 1) & 3)) << 3;
      af[i] = *(const bf16x8*)&bs[(wr + i * 16 + li) * 32 + swz];
      bfr[i] = *(const bf16x8*)&bs[4096 + (wc + i * 16 + li) * 32 + swz];
      bfl[i] = *(const bf16x8*)&bs[8192 + (wc + i * 16 + li) * 32 + swz];
    }
#pragma unroll
    for (int a = 0; a < 4; ++a)
#pragma unroll
      for (int b = 0; b < 4; ++b) {
        acc[a][b] = MFMA16(af[a], bfr[b], acc[a][b]);
        acc[a][b] = MFMA16(af[a], bfl[b], acc[a][b]);
      }
    if (kb + 2 < nk) {
      VMCNTN(6);
    } else {
      VMCNT0();
    }
    __syncthreads();
    cur = (cur == 2) ? 0 : cur + 1;
  }

#pragma unroll
  for (int a = 0; a < 4; ++a)
#pragma unroll
    for (int b = 0; b < 4; ++b)
#pragma unroll
      for (int r = 0; r < 4; ++r) {
        int row = m0 + wr + a * 16 + g * 4 + r;
        int col = n0 + wc + b * 16 + li;
        float bb = col < 1024 ? bias[col] : bias2[col - 1024];
        float v = acc[a][b][r] + bb;
        if (col < 1024) {
          int nn = row >> 11, tt = row & 2047, kbb = tt >> 6, tr = tt & 63;
          int hq = col >> 6, d = col & 63, ks = d >> 5, dc = d & 31;
          size_t base = (((size_t)nn * 16 + hq) * 32 + kbb) * 8192;
          size_t oh = base + ks * 2048 + tr * 32 + (dc & 7) +
                      (((dc >> 3) ^ ((tr >> 1) & 3)) << 3);
          ((u16*)C0)[oh] = bf16_rtn(v);
        } else {
          int cq = col - 1024;
          float vq = v * 1.4426950408889634f;
          u16 hh, ll;
          splitf(vq, hh, ll);
          size_t off = (((size_t)(row >> 11) * 16 + (cq >> 6)) * 2048 + (row & 2047)) * 64 + (cq & 63);
          ((u16*)C1)[off] = hh;
          ((u16*)C2)[off] = ll;
        }
      }
}

// ------------- flash attention, strictly-causal + [0,0], no 1/sqrt(d) -------------
__global__ __launch_bounds__(512) void k_attn(
    const u16* __restrict__ Qh, const u16* __restrict__ Ql,
    const u16* __restrict__ KV, u16* __restrict__ out) {
  const int T = 2048, HD = 64, H = 16, E = 1024;
  int hc = blockIdx.x;
  int h = hc & 15, n = hc >> 4;
  int qq = 15 - (int)blockIdx.y;
  __shared__ u16 KB[3][8192];
  __shared__ u16 P[2][128][36];
  int t = threadIdx.x, lane = t & 63, w = t >> 6;
  int li = lane & 15, g = lane >> 4;

  const size_t nh = (size_t)n * H + h;
  const u16* qhb = Qh + (nh * 2048 + (size_t)qq * 128) * 64;
  const u16* qlb = Ql + (nh * 2048 + (size_t)qq * 128) * 64;
  const u16* kvb = KV + nh * 32 * 8192;

  bf16x8 qh[2], ql[2];
#pragma unroll
  for (int ks = 0; ks < 2; ++ks) {
    qh[ks] = *(const bf16x8*)&qhb[(w * 16 + li) * 64 + ks * 32 + g * 8];
    ql[ks] = *(const bf16x8*)&qlb[(w * 16 + li) * 64 + ks * 32 + g * 8];
  }

#pragma unroll
  for (int j = 0; j < 2; ++j)
    gload16(kvb + (w * 2 + j) * 512 + lane * 8, &KB[0][(w * 2 + j) * 512]);
#pragma unroll
  for (int j = 0; j < 2; ++j)
    gload16(kvb + 8192 + (w * 2 + j) * 512 + lane * 8, &KB[1][(w * 2 + j) * 512]);
  VMCNTN(2);
  __syncthreads();

  float lr[4] = {0.f, 0.f, 0.f, 0.f};
  f32x4 O[4] = {};
  int cur = 0;
  const int nkb = 2 * qq + 2;

  for (int kb = 0; kb < nkb; ++kb) {
    int stb = cur + 2;
    if (stb >= 3) stb -= 3;
    if (kb + 2 < nkb) {
      const u16* src = kvb + (size_t)(kb + 2) * 8192 + (w * 2) * 512 + lane * 8;
#pragma unroll
      for (int j = 0; j < 2; ++j)
        gload16(src + j * 512, &KB[stb][(w * 2 + j) * 512]);
    }

    f32x4 s[4] = {};
#pragma unroll
    for (int ks = 0; ks < 2; ++ks)
#pragma unroll
      for (int c = 0; c < 4; ++c) {
        int jr = c * 16 + li;
        int sw = (jr >> 1) & 3;
        bf16x8 kh = *(const bf16x8*)&KB[cur][ks * 2048 + jr * 32 + ((g ^ sw) << 3)];
        s[c] = MFMA16(qh[ks], kh, s[c]);
        s[c] = MFMA16(ql[ks], kh, s[c]);
      }

    if (kb >= 2 * qq) {
#pragma unroll
      for (int c = 0; c < 4; ++c)
#pragma unroll
        for (int r = 0; r < 4; ++r) {
          int i = qq * 128 + w * 16 + g * 4 + r;
          int j = kb * 64 + c * 16 + li;
          if (!(j < i || (i == 0 && j == 0))) s[c][r] = -INFINITY;
        }
    }

#pragma unroll
    for (int c = 0; c < 4; ++c)
#pragma unroll
      for (int r = 0; r < 4; ++r) {
        float p = exp2_hw(s[c][r]);
        s[c][r] = p;
        lr[r] += p;
      }

#pragma unroll
    for (int c = 0; c < 4; ++c)
#pragma unroll
      for (int r = 0; r < 4; ++r)
        P[c >> 1][w * 16 + g * 4 + r][(c & 1) * 16 + li] = bf16_rtn(s[c][r]);

#pragma unroll
    for (int ks = 0; ks < 2; ++ks) {
      bf16x8 pa = *(const bf16x8*)&P[ks][w * 16 + li][g * 8];
#pragma unroll
      for (int c = 0; c < 4; ++c) {
        int d = c * 16 + li;
        int tc = ks * 4 + g;
        bf16x8 vb = *(const bf16x8*)&KB[cur][4096 + d * 64 + ((tc ^ (d & 7)) << 3)];
        O[c] = MFMA16(pa, vb, O[c]);
      }
    }
    if (kb + 2 < nkb) {
      VMCNTN(2);
    } else {
      VMCNT0();
    }
    __syncthreads();
    cur = (cur == 2) ? 0 : cur + 1;
  }

#pragma unroll
  for (int off = 1; off < 16; off <<= 1)
#pragma unroll
    for (int r = 0; r < 4; ++r) lr[r] += __shfl_xor(lr[r], off, 16);

#pragma unroll
  for (int c = 0; c < 4; ++c)
#pragma unroll
    for (int r = 0; r < 4; ++r) {
      float v = O[c][r] / lr[r];
      size_t row = (size_t)n * T + qq * 128 + w * 16 + g * 4 + r;
      out[row * E + h * HD + c * 16 + li] = bf16_rtn(v);
    }
}

// ---------------------------------------------------------------------------
extern "C" void kernel_launch(void* const* d_in, const int* in_sizes, int n_in,
                              void* d_out, int out_size, void* d_ws, size_t ws_size,
                              hipStream_t stream) {
  const float* kq = (const float*)d_in[0];
  const float* v = (const float*)d_in[1];
  const float* Wk = (const float*)d_in[2];
  const float* bk = (const float*)d_in[3];
  const float* Wq = (const float*)d_in[4];
  const float* bq = (const float*)d_in[5];
  const float* Wv = (const float*)d_in[6];
  const float* bv = (const float*)d_in[7];
  const float* W1 = (const float*)d_in[8];
  const float* b1 = (const float*)d_in[9];
  const float* W2 = (const float*)d_in[10];
  const float* b2 = (const float*)d_in[11];
  float* outp = (float*)d_out;

  char* ws = (char*)d_ws;
  u16* kq_hi = (u16*)(ws + 0);
  u16* v_bf = (u16*)(ws + 8388608);
  u16* hbuf = (u16*)(ws + 0);  // 32MB, aliases kq_hi/v_bf after attention
  u16* WkqT_hi = (u16*)(ws + 33554432);  // 4MB: [WkT | WqT]
  u16* WkqT_lo = (u16*)(ws + 37748736);  // 4MB
  u16* WvT = (u16*)(ws + 41943040);
  u16* W1T = (u16*)(ws + 44040192);
  u16* W2T = (u16*)(ws + 52428800);
  u16* Qh = (u16*)(ws + 60817408);
  u16* Ql = (u16*)(ws + 69206016);
  u16* KV = (u16*)(ws + 77594624);  // 16MB: 1024 slabs x 16KB (K hi + V)
  u16* attn_o = (u16*)(ws + 102760448);
  // total: 111,149,056 bytes

  // --- conversions ---
  k_cvt<<<8192, 256, 0, stream>>>(kq, v, kq_hi, v_bf);
  k_tconvW<<<dim3(32, 32, 3), 256, 0, stream>>>(Wk, Wq, Wv, WkqT_hi, WkqT_lo, WvT);
  k_tconv<<<dim3(128, 32), 256, 0, stream>>>(W1, W1T, 1024, 4096);
  k_tconv<<<dim3(32, 128), 256, 0, stream>>>(W2, W2T, 4096, 1024);

  // --- fused K|Q projection (2-pass split, 3-buf counted vmcnt, XCD swz) ---
  k_gemm_s<<<dim3(16, 32), 256, 0, stream>>>(
      kq_hi, WkqT_hi, WkqT_lo, bk, bq, KV, Qh, Ql, 4096, 2048, 1024);
  // --- V projection ---
  k_gemm<0, 5, 64><<<dim3(16, 32), 256, 0, stream>>>(
      v_bf, WvT, bv, KV, 4096, 1024, 1024);

  // --- attention ---
  k_attn<<<dim3(32, 16), 512, 0, stream>>>(Qh, Ql, KV, attn_o);

  // --- FFN ---
  // FFN1: 256x256 8-wave BK=64 2-buffer (R12-proven best) + fast GELU
  k_gemm2<1, 1><<<dim3(16, 16), 512, 0, stream>>>(
      attn_o, W1T, b1, hbuf, 4096, 4096, 1024);
  // FFN2: BN=128
  k_gemm<0, 0, 128><<<dim3(8, 32), 256, 0, stream>>>(
      hbuf, W2T, b2, outp, 4096, 1024, 4096);
}